// Round 12
// baseline (236.370 us; speedup 1.0000x reference)
//
#include <hip/hip_runtime.h>
#include <hip/hip_bf16.h>

#define D_MODEL 1024
#define D_INNER 2048
#define DT_RANK 64
#define D_STATE 16
#define LSEQ    2048
#define CHUNK   32
#define NCHUNK  (LSEQ / CHUNK)       // 64
#define DN      (D_INNER * D_STATE)  // 32768
#define KSPL_O  4                    // split-K for out-proj
#define KSPL_X  16                   // split-K for x-proj

typedef __attribute__((ext_vector_type(8))) short  short8;
typedef __attribute__((ext_vector_type(4))) short  short4v;
typedef __attribute__((ext_vector_type(4))) float  float4v;
typedef __attribute__((ext_vector_type(4))) unsigned int uint4v;
typedef __hip_bfloat16 bf16;

static __device__ __forceinline__ float b2f(bf16 v) { return __bfloat162float(v); }
static __device__ __forceinline__ bf16  f2b(float v) { return __float2bfloat16(v); }
static __device__ __forceinline__ float us2f(unsigned short u) {
    union { unsigned int i; float f; } cc; cc.i = ((unsigned int)u) << 16; return cc.f;
}
static __device__ __forceinline__ unsigned short f2us(float v) {
    return __bfloat16_as_ushort(__float2bfloat16(v));
}

#define GLOAD_LDS16(g, l)                                                          \
    __builtin_amdgcn_global_load_lds((const __attribute__((address_space(1))) void*)(g), \
                                     (__attribute__((address_space(3))) void*)(l), 16, 0, 0)

// pack/unpack 16 floats <-> 16 bf16 (32 B) at 4B-aligned addresses
static __device__ __forceinline__ void st_bf16x16(bf16* dst, const float* v) {
    uint4v a, b;
    #pragma unroll
    for (int k = 0; k < 4; ++k)
        a[k] = (unsigned)f2us(v[2*k]) | ((unsigned)f2us(v[2*k+1]) << 16);
    #pragma unroll
    for (int k = 0; k < 4; ++k)
        b[k] = (unsigned)f2us(v[8+2*k]) | ((unsigned)f2us(v[8+2*k+1]) << 16);
    ((uint4v*)dst)[0] = a;
    ((uint4v*)dst)[1] = b;
}
static __device__ __forceinline__ void ld_bf16x16(const bf16* src, float* v) {
    uint4v a = ((const uint4v*)src)[0];
    uint4v b = ((const uint4v*)src)[1];
    #pragma unroll
    for (int k = 0; k < 4; ++k) {
        v[2*k]     = us2f((unsigned short)(a[k] & 0xffff));
        v[2*k+1]   = us2f((unsigned short)(a[k] >> 16));
        v[8+2*k]   = us2f((unsigned short)(b[k] & 0xffff));
        v[8+2*k+1] = us2f((unsigned short)(b[k] >> 16));
    }
}

// ---------------------- fused prep: RMSNorm (blocks 0..2047) + weight casts ----
#define N1 (2 * D_INNER * D_MODEL)   // W_in
#define N2 (D_MODEL * D_INNER)       // W_out
#define N3 (96 * D_INNER)            // W_xproj
#define N4 (D_INNER * DT_RANK)       // W_dt
#define NCAST4 ((N1 + N2 + N3 + N4) / 4)
__global__ __launch_bounds__(256)
void prep_kernel(const float* __restrict__ x, const float* __restrict__ nw,
                 bf16* __restrict__ xn,
                 const float* __restrict__ w_in, const float* __restrict__ w_out,
                 const float* __restrict__ w_xp, const float* __restrict__ w_dt,
                 bf16* __restrict__ o_in, bf16* __restrict__ o_out,
                 bf16* __restrict__ o_xp, bf16* __restrict__ o_dt) {
    int t = threadIdx.x;
    if (blockIdx.x < LSEQ) {   // RMSNorm row
        int l = blockIdx.x;
        float4v v = ((const float4v*)(x + (size_t)l * D_MODEL))[t];
        float ssq = v[0]*v[0] + v[1]*v[1] + v[2]*v[2] + v[3]*v[3];
        for (int o = 32; o > 0; o >>= 1) ssq += __shfl_down(ssq, o);
        __shared__ float part[4];
        int lane = t & 63, wid = t >> 6;
        if (lane == 0) part[wid] = ssq;
        __syncthreads();
        float tot = part[0] + part[1] + part[2] + part[3];
        float sc = rsqrtf(tot * (1.0f / D_MODEL) + 1e-5f);
        float4v nv = ((const float4v*)nw)[t];
        bf16* op = xn + (size_t)l * D_MODEL + t * 4;
        op[0] = f2b(v[0] * sc * nv[0]);
        op[1] = f2b(v[1] * sc * nv[1]);
        op[2] = f2b(v[2] * sc * nv[2]);
        op[3] = f2b(v[3] * sc * nv[3]);
        return;
    }
    int i4 = (blockIdx.x - LSEQ) * 256 + t;
    if (i4 >= NCAST4) return;
    const float* src; bf16* dst; int base;
    if (i4 < N1 / 4)                { src = w_in;  dst = o_in;  base = 0; }
    else if (i4 < (N1 + N2) / 4)    { src = w_out; dst = o_out; base = N1 / 4; }
    else if (i4 < (N1+N2+N3) / 4)   { src = w_xp;  dst = o_xp;  base = (N1+N2) / 4; }
    else                            { src = w_dt;  dst = o_dt;  base = (N1+N2+N3) / 4; }
    int j = i4 - base;
    float4v v = ((const float4v*)src)[j];
    bf16* o = dst + j * 4;
    o[0] = f2b(v[0]); o[1] = f2b(v[1]); o[2] = f2b(v[2]); o[3] = f2b(v[3]);
}

// ---- fast NT GEMM: 512 threads / 8 waves, wave tile 32x64, BK=64, dbuf LDS ---
// C[M,N] = A[M,K]*B[N,K]^T. Tiles 128x128. kLen%64==0.
// LDS physical 16B-chunk = logical chunk ^ (row&7) -> conflict-free stage+read.
// MODE 0: outB = bf16(acc)                       (xz)
// MODE 2: outB = bf16(softplus(acc+bias[n]))     (delta)
// MODE 5: outB[z-slice] = bf16(acc)  bf16 split-K partials (x-proj, out-proj)
template <int MODE>
__global__ __launch_bounds__(512)
void gemm_fast(const bf16* __restrict__ Ab, const bf16* __restrict__ Bb,
               int M, int N, int K, int kLen,
               float* __restrict__ outF, bf16* __restrict__ outB,
               const float* __restrict__ bias) {
    __shared__ short As[2][128 * 64];   // 16 KB per buffer
    __shared__ short Bs[2][128 * 64];
    const short* Ap = (const short*)Ab;
    const short* Bp = (const short*)Bb;

    int t = threadIdx.x;
    int lane = t & 63, wid = t >> 6;            // 8 waves
    int mBase = blockIdx.y * 128, nBase = blockIdx.x * 128;
    int kBase = blockIdx.z * kLen;
    int wm = 32 * (wid >> 1), wn = 64 * (wid & 1);   // wave tile 32x64
    int lr = lane & 15, quad = lane >> 4;

    // staging: wave wid owns rows [16*wid, 16*wid+16); 2 instrs of 8 rows each.
    int srow = 16 * wid + (lane >> 3);
    int cg2 = (lane & 7) ^ (lane >> 3);         // global chunk for phys chunk lane&7
    const short* gA = Ap + (size_t)(mBase + srow) * K + cg2 * 8;
    const short* gB = Bp + (size_t)(nBase + srow) * K + cg2 * 8;

    float4v acc[2][4] = {};

    // prologue: stage first K-slab into buf 0
    #pragma unroll
    for (int g = 0; g < 2; ++g) {
        GLOAD_LDS16(gA + (size_t)g * 8 * K + kBase, &As[0][(16 * wid + g * 8) * 64]);
        GLOAD_LDS16(gB + (size_t)g * 8 * K + kBase, &Bs[0][(16 * wid + g * 8) * 64]);
    }

    int p = 0;
    for (int kt = kBase; kt < kBase + kLen; kt += 64, p ^= 1) {
        __syncthreads();   // drains buf[p] loads; all waves past buf[p^1] reads
        if (kt + 64 < kBase + kLen) {
            int kn = kt + 64, q = p ^ 1;
            #pragma unroll
            for (int g = 0; g < 2; ++g) {
                GLOAD_LDS16(gA + (size_t)g * 8 * K + kn, &As[q][(16 * wid + g * 8) * 64]);
                GLOAD_LDS16(gB + (size_t)g * 8 * K + kn, &Bs[q][(16 * wid + g * 8) * 64]);
            }
        }
        #pragma unroll
        for (int s = 0; s < 2; ++s) {
            short8 af[2], bfr[4];
            #pragma unroll
            for (int i = 0; i < 2; ++i) {
                int row = wm + i * 16 + lr;
                af[i] = *(const short8*)&As[p][row * 64 + (((s * 4 + quad) ^ (lr & 7)) * 8)];
            }
            #pragma unroll
            for (int j = 0; j < 4; ++j) {
                int row = wn + j * 16 + lr;
                bfr[j] = *(const short8*)&Bs[p][row * 64 + (((s * 4 + quad) ^ (lr & 7)) * 8)];
            }
            #pragma unroll
            for (int i = 0; i < 2; ++i)
                #pragma unroll
                for (int j = 0; j < 4; ++j)
                    acc[i][j] = __builtin_amdgcn_mfma_f32_16x16x32_bf16(af[i], bfr[j], acc[i][j], 0, 0, 0);
        }
    }

    #pragma unroll
    for (int i = 0; i < 2; ++i) {
        #pragma unroll
        for (int j = 0; j < 4; ++j) {
            #pragma unroll
            for (int r = 0; r < 4; ++r) {
                int gm = mBase + wm + i * 16 + quad * 4 + r;
                int gn = nBase + wn + j * 16 + lr;
                float v = acc[i][j][r];
                if (MODE == 0) {
                    outB[(size_t)gm * N + gn] = f2b(v);
                } else if (MODE == 2) {
                    v += bias[gn];
                    v = (v > 20.0f) ? v : log1pf(__expf(v));
                    outB[(size_t)gm * N + gn] = f2b(v);
                } else {  // MODE 5: bf16 split-K partials
                    outB[((size_t)blockIdx.z * M + gm) * N + gn] = f2b(v);
                }
            }
        }
    }
}

// --------------- x_proj reduce: dbc = sum_z bf16 part, + dt bf16 cast ---------
__global__ __launch_bounds__(128)
void reduce_xproj(const bf16* __restrict__ part, float* __restrict__ dbc,
                  bf16* __restrict__ dtb) {
    int m = blockIdx.x, j = threadIdx.x;
    if (j >= 96) return;
    float v = 0.0f;
    #pragma unroll
    for (int z = 0; z < KSPL_X; ++z)
        v += b2f(part[((size_t)z * LSEQ + m) * 128 + j]);
    dbc[(size_t)m * 96 + j] = v;
    if (j < DT_RANK) dtb[(size_t)m * DT_RANK + j] = f2b(v);
}

// --------- out reduce: d_out = sum_z bf16 part + x (residual fused) -----------
__global__ __launch_bounds__(256)
void reduce_out(const bf16* __restrict__ part, const float* __restrict__ x,
                float* __restrict__ out) {
    int i = blockIdx.x * 256 + threadIdx.x;   // float4 over M*N/4
    const size_t MN = (size_t)LSEQ * D_MODEL;
    float a0 = 0, a1 = 0, a2 = 0, a3 = 0;
    #pragma unroll
    for (int z = 0; z < KSPL_O; ++z) {
        short4v b = *(const short4v*)((const short*)part + z * MN + (size_t)i * 4);
        a0 += us2f((unsigned short)b[0]);
        a1 += us2f((unsigned short)b[1]);
        a2 += us2f((unsigned short)b[2]);
        a3 += us2f((unsigned short)b[3]);
    }
    float4v xv = ((const float4v*)x)[i];
    float4v o = {a0 + xv[0], a1 + xv[1], a2 + xv[2], a3 + xv[3]};
    ((float4v*)out)[i] = o;
}

// ------------- depthwise causal conv+SiLU, 2 channels x 4 timesteps/thread ----
__global__ void conv_kernel(const bf16* __restrict__ xz, const float* __restrict__ cw,
                            const float* __restrict__ cb, bf16* __restrict__ xsb) {
    int idx = blockIdx.x * 256 + threadIdx.x;   // over (LSEQ/4)*(D_INNER/2)
    int c = (idx & (D_INNER / 2 - 1)) * 2;
    int l0 = (idx >> 10) * 4;
    float4v wA = ((const float4v*)cw)[c];       // cw row c: 4 floats
    float4v wB = ((const float4v*)cw)[c + 1];
    float bA = cb[c], bB = cb[c + 1];
    const unsigned int* col = (const unsigned int*)((const unsigned short*)xz + c);
    float vA[7], vB[7];
    #pragma unroll
    for (int j = 0; j < 7; ++j) {
        int l = l0 - 3 + j;
        if (l >= 0) {
            unsigned int u = col[(size_t)l * D_INNER];   // 2 bf16 = 4B, stride 2*D_INNER shorts
            vA[j] = us2f((unsigned short)(u & 0xffff));
            vB[j] = us2f((unsigned short)(u >> 16));
        } else { vA[j] = 0.0f; vB[j] = 0.0f; }
    }
    #pragma unroll
    for (int j = 0; j < 4; ++j) {
        float aA = bA + vA[j]*wA[0] + vA[j+1]*wA[1] + vA[j+2]*wA[2] + vA[j+3]*wA[3];
        float aB = bB + vB[j]*wB[0] + vB[j+1]*wB[1] + vB[j+2]*wB[2] + vB[j+3]*wB[3];
        float sA = aA * (1.0f / (1.0f + __expf(-aA)));
        float sB = aB * (1.0f / (1.0f + __expf(-aB)));
        unsigned int o = (unsigned int)f2us(sA) | ((unsigned int)f2us(sB) << 16);
        *(unsigned int*)((unsigned short*)xsb + (size_t)(l0 + j) * D_INNER + c) = o;
    }
}

// ------------------------------- chunked selective scan, states in registers --
// A2 = A*log2(e) precomputed -> a = exp2(dv*A2): saves one v_mul per (l,n).
// PASS 0 decay product via identity  prod_l exp(dv_l*A) = exp2(A2 * sum_l dv_l):
// replaces 16 v_mul/l with one scalar add/l + 16 exps per chunk.
template <int PASS>
__global__ __launch_bounds__(256)
void scan2(const bf16* __restrict__ delta, const bf16* __restrict__ xsb,
           const float* __restrict__ dbc, const bf16* __restrict__ xz,
           const float* __restrict__ A_log, const float* __restrict__ Dw,
           const bf16* __restrict__ Hinit,
           bf16* __restrict__ P, bf16* __restrict__ S, bf16* __restrict__ yg) {
    __shared__ float bc[CHUNK][32];   // [l][B(16)|C(16)]
    int t = threadIdx.x;
    int d = blockIdx.x * 256 + t;
    int c = blockIdx.y;
    int l0 = c * CHUNK;

    {   // stage B,C for this chunk: 32 rows x 32 floats = 4 KB
        int row = t >> 3, col = (t & 7) * 4;
        *(float4v*)&bc[row][col] = *(const float4v*)&dbc[(size_t)(l0 + row) * 96 + 64 + col];
    }
    __syncthreads();

    float A2[16], h[16];
    #pragma unroll
    for (int n = 0; n < 16; ++n)
        A2[n] = -__expf(A_log[(size_t)d * 16 + n]) * 1.44269504f;   // A * log2(e)
    float sdv = 0.0f;
    if (PASS == 0) {
        #pragma unroll
        for (int n = 0; n < 16; ++n) h[n] = 0.0f;
    } else {
        ld_bf16x16(Hinit + (size_t)c * DN + (size_t)d * 16, h);
    }
    float Dd = (PASS == 1) ? Dw[d] : 0.0f;

    for (int i = 0; i < CHUNK; ++i) {
        int l = l0 + i;
        float dv = b2f(delta[(size_t)l * D_INNER + d]);
        float xv = b2f(xsb[(size_t)l * D_INNER + d]);
        float u = dv * xv;
        if (PASS == 0) sdv += dv;
        #pragma unroll
        for (int n = 0; n < 16; ++n) {
            float a = exp2f(dv * A2[n]);
            h[n] = fmaf(a, h[n], bc[i][n] * u);
        }
        if (PASS == 1) {
            float y = xv * Dd;
            #pragma unroll
            for (int n = 0; n < 16; ++n) y = fmaf(h[n], bc[i][16 + n], y);
            float r = b2f(xz[(size_t)l * (2 * D_INNER) + D_INNER + d]);
            float g = r * (1.0f / (1.0f + __expf(-r)));
            yg[(size_t)l * D_INNER + d] = f2b(y * g);
        }
    }
    if (PASS == 0) {
        float pr[16];
        #pragma unroll
        for (int n = 0; n < 16; ++n) pr[n] = exp2f(A2[n] * sdv);
        st_bf16x16(P + (size_t)c * DN + (size_t)d * 16, pr);
        st_bf16x16(S + (size_t)c * DN + (size_t)d * 16, h);
    }
}

// Sequential compose over chunks: h_init[c+1] = P[c]*h_init[c] + S[c].  (bf16 io)
__global__ __launch_bounds__(256)
void scan_mid(const bf16* __restrict__ P, const bf16* __restrict__ S,
              bf16* __restrict__ Hinit) {
    int idx = blockIdx.x * 256 + threadIdx.x;   // over DN
    float h = 0.0f;
    for (int c0 = 0; c0 < NCHUNK; c0 += 8) {
        float p[8], s[8];
        #pragma unroll
        for (int j = 0; j < 8; ++j) {
            p[j] = b2f(P[(size_t)(c0 + j) * DN + idx]);
            s[j] = b2f(S[(size_t)(c0 + j) * DN + idx]);
        }
        #pragma unroll
        for (int j = 0; j < 8; ++j) {
            Hinit[(size_t)(c0 + j) * DN + idx] = f2b(h);
            h = fmaf(p[j], h, s[j]);
        }
    }
}

// -------------------------------------------------------------- launcher ----
extern "C" void kernel_launch(void* const* d_in, const int* in_sizes, int n_in,
                              void* d_out, int out_size, void* d_ws, size_t ws_size,
                              hipStream_t stream) {
    const float* x       = (const float*)d_in[0];
    const float* W_in    = (const float*)d_in[1];
    const float* conv_w  = (const float*)d_in[2];
    const float* conv_b  = (const float*)d_in[3];
    const float* W_xproj = (const float*)d_in[4];
    const float* W_dt    = (const float*)d_in[5];
    const float* b_dt    = (const float*)d_in[6];
    const float* A_log   = (const float*)d_in[7];
    const float* Dw      = (const float*)d_in[8];
    const float* W_out   = (const float*)d_in[9];
    const float* norm_w  = (const float*)d_in[10];

    char* w = (char*)d_ws;
    bf16* W_in_b    = (bf16*)w; w += (size_t)2 * D_INNER * D_MODEL * 2;   // 8 MB
    bf16* W_out_b   = (bf16*)w; w += (size_t)D_MODEL * D_INNER * 2;       // 4 MB
    bf16* W_xproj_b = (bf16*)w; w += (size_t)128 * D_INNER * 2;           // 512 KB (rows 96..127 pad)
    bf16* W_dt_b    = (bf16*)w; w += (size_t)D_INNER * DT_RANK * 2;       // 256 KB
    char* reuse0 = w;   // aliased by out_part after scan
    bf16* xn        = (bf16*)w; w += (size_t)LSEQ * D_MODEL * 2;          // 4 MB
    bf16* xz        = (bf16*)w; w += (size_t)LSEQ * 2 * D_INNER * 2;      // 16 MB
    bf16* xsb       = (bf16*)w; w += (size_t)LSEQ * D_INNER * 2;          // 8 MB
    bf16* delta     = (bf16*)w; w += (size_t)LSEQ * D_INNER * 2;          // 8 MB  (36 MB pool)
    float* dbc      = (float*)w; w += (size_t)LSEQ * 96 * 4;              // 768 KB
    bf16* dtb       = (bf16*)w; w += (size_t)LSEQ * DT_RANK * 2;          // 256 KB
    bf16* yg        = (bf16*)w; w += (size_t)LSEQ * D_INNER * 2;          // 8 MB
    bf16* Pbuf      = (bf16*)w; w += (size_t)NCHUNK * DN * 2;             // 4 MB
    bf16* Sbuf      = (bf16*)w; w += (size_t)NCHUNK * DN * 2;             // 4 MB
    bf16* Hinit     = (bf16*)w; w += (size_t)NCHUNK * DN * 2;             // 4 MB
    bf16* xp_part   = (bf16*)w; w += (size_t)KSPL_X * LSEQ * 128 * 2;     // 8 MB
    bf16* out_part  = (bf16*)reuse0;   // 16 MB bf16, aliases xn/xz (dead by then)

    prep_kernel<<<LSEQ + (NCAST4 + 255) / 256, 256, 0, stream>>>(
        x, norm_w, xn, W_in, W_out, W_xproj, W_dt, W_in_b, W_out_b, W_xproj_b, W_dt_b);

    // in_proj: (2048 x 4096) = xn (2048x1024) * W_in^T
    gemm_fast<0><<<dim3(4096 / 128, 2048 / 128, 1), 512, 0, stream>>>(
        xn, W_in_b, 2048, 4096, 1024, 1024, nullptr, xz, nullptr);

    conv_kernel<<<(LSEQ / 4) * (D_INNER / 2) / 256, 256, 0, stream>>>(xz, conv_w, conv_b, xsb);

    // x_proj: (2048 x 96) = xsb (2048x2048) * W_xproj^T, split-K=16, bf16 partials
    gemm_fast<5><<<dim3(1, 2048 / 128, KSPL_X), 512, 0, stream>>>(
        xsb, W_xproj_b, 2048, 128, 2048, 2048 / KSPL_X, nullptr, xp_part, nullptr);
    reduce_xproj<<<LSEQ, 128, 0, stream>>>(xp_part, dbc, dtb);

    // delta: (2048 x 2048) = dtb (2048x64) * W_dt^T, softplus+bias epilogue
    gemm_fast<2><<<dim3(2048 / 128, 2048 / 128, 1), 512, 0, stream>>>(
        dtb, W_dt_b, 2048, 2048, 64, 64, nullptr, delta, b_dt);

    dim3 sgrid(D_INNER / 256, NCHUNK);
    scan2<0><<<sgrid, 256, 0, stream>>>(delta, xsb, dbc, xz, A_log, Dw,
                                        nullptr, Pbuf, Sbuf, nullptr);
    scan_mid<<<DN / 256, 256, 0, stream>>>(Pbuf, Sbuf, Hinit);
    scan2<1><<<sgrid, 256, 0, stream>>>(delta, xsb, dbc, xz, A_log, Dw,
                                        Hinit, nullptr, nullptr, yg);

    // out_proj: (2048 x 1024) = yg (2048x2048) * W_out^T, split-K=4, bf16 partials
    gemm_fast<5><<<dim3(1024 / 128, 2048 / 128, KSPL_O), 512, 0, stream>>>(
        yg, W_out_b, 2048, 1024, 2048, 2048 / KSPL_O, nullptr, out_part, nullptr);
    reduce_out<<<LSEQ * D_MODEL / 4 / 256, 256, 0, stream>>>(out_part, x, (float*)d_out);
}

// Round 13
// 227.836 us; speedup vs baseline: 1.0375x; 1.0375x over previous
//
#include <hip/hip_runtime.h>
#include <hip/hip_bf16.h>

#define D_MODEL 1024
#define D_INNER 2048
#define DT_RANK 64
#define D_STATE 16
#define LSEQ    2048
#define CHUNK   32
#define NCHUNK  (LSEQ / CHUNK)       // 64
#define DN      (D_INNER * D_STATE)  // 32768
#define KSPL_O  4                    // split-K for out-proj
#define KSPL_X  32                   // split-K for x-proj

typedef __attribute__((ext_vector_type(8))) short  short8;
typedef __attribute__((ext_vector_type(4))) short  short4v;
typedef __attribute__((ext_vector_type(4))) float  float4v;
typedef __attribute__((ext_vector_type(4))) unsigned int uint4v;
typedef __hip_bfloat16 bf16;

static __device__ __forceinline__ float b2f(bf16 v) { return __bfloat162float(v); }
static __device__ __forceinline__ bf16  f2b(float v) { return __float2bfloat16(v); }
static __device__ __forceinline__ float us2f(unsigned short u) {
    union { unsigned int i; float f; } cc; cc.i = ((unsigned int)u) << 16; return cc.f;
}
static __device__ __forceinline__ unsigned short f2us(float v) {
    return __bfloat16_as_ushort(__float2bfloat16(v));
}
// exact softplus, cheap: log1p(e^v) = max(v,0) + log(1+e^-|v|)
static __device__ __forceinline__ float softplus_f(float v) {
    return fmaxf(v, 0.0f) + __logf(1.0f + __expf(-fabsf(v)));
}

#define GLOAD_LDS16(g, l)                                                          \
    __builtin_amdgcn_global_load_lds((const __attribute__((address_space(1))) void*)(g), \
                                     (__attribute__((address_space(3))) void*)(l), 16, 0, 0)

// pack/unpack 16 floats <-> 16 bf16 (32 B) at 4B-aligned addresses
static __device__ __forceinline__ void st_bf16x16(bf16* dst, const float* v) {
    uint4v a, b;
    #pragma unroll
    for (int k = 0; k < 4; ++k)
        a[k] = (unsigned)f2us(v[2*k]) | ((unsigned)f2us(v[2*k+1]) << 16);
    #pragma unroll
    for (int k = 0; k < 4; ++k)
        b[k] = (unsigned)f2us(v[8+2*k]) | ((unsigned)f2us(v[8+2*k+1]) << 16);
    ((uint4v*)dst)[0] = a;
    ((uint4v*)dst)[1] = b;
}
static __device__ __forceinline__ void ld_bf16x16(const bf16* src, float* v) {
    uint4v a = ((const uint4v*)src)[0];
    uint4v b = ((const uint4v*)src)[1];
    #pragma unroll
    for (int k = 0; k < 4; ++k) {
        v[2*k]     = us2f((unsigned short)(a[k] & 0xffff));
        v[2*k+1]   = us2f((unsigned short)(a[k] >> 16));
        v[8+2*k]   = us2f((unsigned short)(b[k] & 0xffff));
        v[8+2*k+1] = us2f((unsigned short)(b[k] >> 16));
    }
}

// ---------------------- fused prep: RMSNorm (blocks 0..2047) + weight casts ----
#define N1 (2 * D_INNER * D_MODEL)   // W_in
#define N2 (D_MODEL * D_INNER)       // W_out
#define N3 (96 * D_INNER)            // W_xproj
#define N4 (D_INNER * DT_RANK)       // W_dt
#define NCAST4 ((N1 + N2 + N3 + N4) / 4)
__global__ __launch_bounds__(256)
void prep_kernel(const float* __restrict__ x, const float* __restrict__ nw,
                 bf16* __restrict__ xn,
                 const float* __restrict__ w_in, const float* __restrict__ w_out,
                 const float* __restrict__ w_xp, const float* __restrict__ w_dt,
                 bf16* __restrict__ o_in, bf16* __restrict__ o_out,
                 bf16* __restrict__ o_xp, bf16* __restrict__ o_dt) {
    int t = threadIdx.x;
    if (blockIdx.x < LSEQ) {   // RMSNorm row
        int l = blockIdx.x;
        float4v v = ((const float4v*)(x + (size_t)l * D_MODEL))[t];
        float ssq = v[0]*v[0] + v[1]*v[1] + v[2]*v[2] + v[3]*v[3];
        for (int o = 32; o > 0; o >>= 1) ssq += __shfl_down(ssq, o);
        __shared__ float part[4];
        int lane = t & 63, wid = t >> 6;
        if (lane == 0) part[wid] = ssq;
        __syncthreads();
        float tot = part[0] + part[1] + part[2] + part[3];
        float sc = rsqrtf(tot * (1.0f / D_MODEL) + 1e-5f);
        float4v nv = ((const float4v*)nw)[t];
        bf16* op = xn + (size_t)l * D_MODEL + t * 4;
        op[0] = f2b(v[0] * sc * nv[0]);
        op[1] = f2b(v[1] * sc * nv[1]);
        op[2] = f2b(v[2] * sc * nv[2]);
        op[3] = f2b(v[3] * sc * nv[3]);
        return;
    }
    int i4 = (blockIdx.x - LSEQ) * 256 + t;
    if (i4 >= NCAST4) return;
    const float* src; bf16* dst; int base;
    if (i4 < N1 / 4)                { src = w_in;  dst = o_in;  base = 0; }
    else if (i4 < (N1 + N2) / 4)    { src = w_out; dst = o_out; base = N1 / 4; }
    else if (i4 < (N1+N2+N3) / 4)   { src = w_xp;  dst = o_xp;  base = (N1+N2) / 4; }
    else                            { src = w_dt;  dst = o_dt;  base = (N1+N2+N3) / 4; }
    int j = i4 - base;
    float4v v = ((const float4v*)src)[j];
    bf16* o = dst + j * 4;
    o[0] = f2b(v[0]); o[1] = f2b(v[1]); o[2] = f2b(v[2]); o[3] = f2b(v[3]);
}

// ---- fast NT GEMM: 512 threads / 8 waves, wave tile 32x64, BK=64, dbuf LDS ---
// MODE 0: outB = bf16(acc)                       (xz)
// MODE 5: outB[z-slice] = bf16(acc)  bf16 split-K partials (x-proj, out-proj)
template <int MODE>
__global__ __launch_bounds__(512)
void gemm_fast(const bf16* __restrict__ Ab, const bf16* __restrict__ Bb,
               int M, int N, int K, int kLen,
               float* __restrict__ outF, bf16* __restrict__ outB,
               const float* __restrict__ bias) {
    __shared__ short As[2][128 * 64];   // 16 KB per buffer
    __shared__ short Bs[2][128 * 64];
    const short* Ap = (const short*)Ab;
    const short* Bp = (const short*)Bb;

    int t = threadIdx.x;
    int lane = t & 63, wid = t >> 6;            // 8 waves
    int mBase = blockIdx.y * 128, nBase = blockIdx.x * 128;
    int kBase = blockIdx.z * kLen;
    int wm = 32 * (wid >> 1), wn = 64 * (wid & 1);   // wave tile 32x64
    int lr = lane & 15, quad = lane >> 4;

    // staging: wave wid owns rows [16*wid, 16*wid+16); 2 instrs of 8 rows each.
    int srow = 16 * wid + (lane >> 3);
    int cg2 = (lane & 7) ^ (lane >> 3);         // global chunk for phys chunk lane&7
    const short* gA = Ap + (size_t)(mBase + srow) * K + cg2 * 8;
    const short* gB = Bp + (size_t)(nBase + srow) * K + cg2 * 8;

    float4v acc[2][4] = {};

    // prologue: stage first K-slab into buf 0
    #pragma unroll
    for (int g = 0; g < 2; ++g) {
        GLOAD_LDS16(gA + (size_t)g * 8 * K + kBase, &As[0][(16 * wid + g * 8) * 64]);
        GLOAD_LDS16(gB + (size_t)g * 8 * K + kBase, &Bs[0][(16 * wid + g * 8) * 64]);
    }

    int p = 0;
    for (int kt = kBase; kt < kBase + kLen; kt += 64, p ^= 1) {
        __syncthreads();   // drains buf[p] loads; all waves past buf[p^1] reads
        if (kt + 64 < kBase + kLen) {
            int kn = kt + 64, q = p ^ 1;
            #pragma unroll
            for (int g = 0; g < 2; ++g) {
                GLOAD_LDS16(gA + (size_t)g * 8 * K + kn, &As[q][(16 * wid + g * 8) * 64]);
                GLOAD_LDS16(gB + (size_t)g * 8 * K + kn, &Bs[q][(16 * wid + g * 8) * 64]);
            }
        }
        #pragma unroll
        for (int s = 0; s < 2; ++s) {
            short8 af[2], bfr[4];
            #pragma unroll
            for (int i = 0; i < 2; ++i) {
                int row = wm + i * 16 + lr;
                af[i] = *(const short8*)&As[p][row * 64 + (((s * 4 + quad) ^ (lr & 7)) * 8)];
            }
            #pragma unroll
            for (int j = 0; j < 4; ++j) {
                int row = wn + j * 16 + lr;
                bfr[j] = *(const short8*)&Bs[p][row * 64 + (((s * 4 + quad) ^ (lr & 7)) * 8)];
            }
            #pragma unroll
            for (int i = 0; i < 2; ++i)
                #pragma unroll
                for (int j = 0; j < 4; ++j)
                    acc[i][j] = __builtin_amdgcn_mfma_f32_16x16x32_bf16(af[i], bfr[j], acc[i][j], 0, 0, 0);
        }
    }

    #pragma unroll
    for (int i = 0; i < 2; ++i) {
        #pragma unroll
        for (int j = 0; j < 4; ++j) {
            #pragma unroll
            for (int r = 0; r < 4; ++r) {
                int gm = mBase + wm + i * 16 + quad * 4 + r;
                int gn = nBase + wn + j * 16 + lr;
                float v = acc[i][j][r];
                if (MODE == 0) {
                    outB[(size_t)gm * N + gn] = f2b(v);
                } else {  // MODE 5: bf16 split-K partials
                    outB[((size_t)blockIdx.z * M + gm) * N + gn] = f2b(v);
                }
            }
        }
    }
}

// ------- delta GEMM: 64x64 tile, 256 thr, single-shot K=64, softplus fused ----
// C[2048,2048] = dtb[2048,64] * W_dt[2048,64]^T;  grid 32x32 = 1024 blocks.
__global__ __launch_bounds__(256)
void gemm_delta(const bf16* __restrict__ Ab, const bf16* __restrict__ Bb,
                bf16* __restrict__ outB, const float* __restrict__ bias) {
    const int K = 64, N = 2048;
    __shared__ short As[64 * 64];   // 8 KB
    __shared__ short Bs[64 * 64];   // 8 KB
    int t = threadIdx.x;
    int lane = t & 63, wid = t >> 6;   // 4 waves
    int mBase = blockIdx.y * 64, nBase = blockIdx.x * 64;
    int lr = lane & 15, quad = lane >> 4;

    // staging: wave wid stages rows [16*wid,16*wid+16) of A and B (2 GLOADs each)
    int srow = 16 * wid + (lane >> 3);
    int cg2 = (lane & 7) ^ (lane >> 3);
    const short* gA = (const short*)Ab + (size_t)(mBase + srow) * K + cg2 * 8;
    const short* gB = (const short*)Bb + (size_t)(nBase + srow) * K + cg2 * 8;
    #pragma unroll
    for (int g = 0; g < 2; ++g) {
        GLOAD_LDS16(gA + (size_t)g * 8 * K, &As[(16 * wid + g * 8) * 64]);
        GLOAD_LDS16(gB + (size_t)g * 8 * K, &Bs[(16 * wid + g * 8) * 64]);
    }
    __syncthreads();

    float4v acc[4] = {};
    #pragma unroll
    for (int s = 0; s < 2; ++s) {
        short8 af = *(const short8*)&As[(16 * wid + lr) * 64 + (((s * 4 + quad) ^ (lr & 7)) * 8)];
        #pragma unroll
        for (int j = 0; j < 4; ++j) {
            short8 bf8 = *(const short8*)&Bs[(j * 16 + lr) * 64 + (((s * 4 + quad) ^ (lr & 7)) * 8)];
            acc[j] = __builtin_amdgcn_mfma_f32_16x16x32_bf16(af, bf8, acc[j], 0, 0, 0);
        }
    }

    #pragma unroll
    for (int j = 0; j < 4; ++j) {
        #pragma unroll
        for (int r = 0; r < 4; ++r) {
            int gm = mBase + 16 * wid + quad * 4 + r;
            int gn = nBase + j * 16 + lr;
            float v = softplus_f(acc[j][r] + bias[gn]);
            outB[(size_t)gm * N + gn] = f2b(v);
        }
    }
}

// --------------- x_proj reduce: dbc = sum_z bf16 part, + dt bf16 cast ---------
__global__ __launch_bounds__(128)
void reduce_xproj(const bf16* __restrict__ part, float* __restrict__ dbc,
                  bf16* __restrict__ dtb) {
    int m = blockIdx.x, j = threadIdx.x;
    if (j >= 96) return;
    float v = 0.0f;
    #pragma unroll
    for (int z = 0; z < KSPL_X; ++z)
        v += b2f(part[((size_t)z * LSEQ + m) * 128 + j]);
    dbc[(size_t)m * 96 + j] = v;
    if (j < DT_RANK) dtb[(size_t)m * DT_RANK + j] = f2b(v);
}

// --------- out reduce: d_out = sum_z bf16 part + x (residual fused) -----------
__global__ __launch_bounds__(256)
void reduce_out(const bf16* __restrict__ part, const float* __restrict__ x,
                float* __restrict__ out) {
    int i = blockIdx.x * 256 + threadIdx.x;   // float4 over M*N/4
    const size_t MN = (size_t)LSEQ * D_MODEL;
    float a0 = 0, a1 = 0, a2 = 0, a3 = 0;
    #pragma unroll
    for (int z = 0; z < KSPL_O; ++z) {
        short4v b = *(const short4v*)((const short*)part + z * MN + (size_t)i * 4);
        a0 += us2f((unsigned short)b[0]);
        a1 += us2f((unsigned short)b[1]);
        a2 += us2f((unsigned short)b[2]);
        a3 += us2f((unsigned short)b[3]);
    }
    float4v xv = ((const float4v*)x)[i];
    float4v o = {a0 + xv[0], a1 + xv[1], a2 + xv[2], a3 + xv[3]};
    ((float4v*)out)[i] = o;
}

// ------------- depthwise causal conv+SiLU, 2 channels x 4 timesteps/thread ----
__global__ void conv_kernel(const bf16* __restrict__ xz, const float* __restrict__ cw,
                            const float* __restrict__ cb, bf16* __restrict__ xsb) {
    int idx = blockIdx.x * 256 + threadIdx.x;   // over (LSEQ/4)*(D_INNER/2)
    int c = (idx & (D_INNER / 2 - 1)) * 2;
    int l0 = (idx >> 10) * 4;
    float4v wA = ((const float4v*)cw)[c];       // cw row c: 4 floats
    float4v wB = ((const float4v*)cw)[c + 1];
    float bA = cb[c], bB = cb[c + 1];
    const unsigned int* col = (const unsigned int*)((const unsigned short*)xz + c);
    float vA[7], vB[7];
    #pragma unroll
    for (int j = 0; j < 7; ++j) {
        int l = l0 - 3 + j;
        if (l >= 0) {
            unsigned int u = col[(size_t)l * D_INNER];   // 2 bf16 = 4B, stride 2*D_INNER shorts
            vA[j] = us2f((unsigned short)(u & 0xffff));
            vB[j] = us2f((unsigned short)(u >> 16));
        } else { vA[j] = 0.0f; vB[j] = 0.0f; }
    }
    #pragma unroll
    for (int j = 0; j < 4; ++j) {
        float aA = bA + vA[j]*wA[0] + vA[j+1]*wA[1] + vA[j+2]*wA[2] + vA[j+3]*wA[3];
        float aB = bB + vB[j]*wB[0] + vB[j+1]*wB[1] + vB[j+2]*wB[2] + vB[j+3]*wB[3];
        float sA = aA * (1.0f / (1.0f + __expf(-aA)));
        float sB = aB * (1.0f / (1.0f + __expf(-aB)));
        unsigned int o = (unsigned int)f2us(sA) | ((unsigned int)f2us(sB) << 16);
        *(unsigned int*)((unsigned short*)xsb + (size_t)(l0 + j) * D_INNER + c) = o;
    }
}

// ------------------------------- chunked selective scan, states in registers --
template <int PASS>
__global__ __launch_bounds__(256)
void scan2(const bf16* __restrict__ delta, const bf16* __restrict__ xsb,
           const float* __restrict__ dbc, const bf16* __restrict__ xz,
           const float* __restrict__ A_log, const float* __restrict__ Dw,
           const bf16* __restrict__ Hinit,
           bf16* __restrict__ P, bf16* __restrict__ S, bf16* __restrict__ yg) {
    __shared__ float bc[CHUNK][32];   // [l][B(16)|C(16)]
    int t = threadIdx.x;
    int d = blockIdx.x * 256 + t;
    int c = blockIdx.y;
    int l0 = c * CHUNK;

    {   // stage B,C for this chunk: 32 rows x 32 floats = 4 KB
        int row = t >> 3, col = (t & 7) * 4;
        *(float4v*)&bc[row][col] = *(const float4v*)&dbc[(size_t)(l0 + row) * 96 + 64 + col];
    }
    __syncthreads();

    float A2[16], h[16];
    #pragma unroll
    for (int n = 0; n < 16; ++n)
        A2[n] = -__expf(A_log[(size_t)d * 16 + n]) * 1.44269504f;   // A * log2(e)
    float sdv = 0.0f;
    if (PASS == 0) {
        #pragma unroll
        for (int n = 0; n < 16; ++n) h[n] = 0.0f;
    } else {
        ld_bf16x16(Hinit + (size_t)c * DN + (size_t)d * 16, h);
    }
    float Dd = (PASS == 1) ? Dw[d] : 0.0f;

    for (int i = 0; i < CHUNK; ++i) {
        int l = l0 + i;
        float dv = b2f(delta[(size_t)l * D_INNER + d]);
        float xv = b2f(xsb[(size_t)l * D_INNER + d]);
        float u = dv * xv;
        if (PASS == 0) sdv += dv;
        #pragma unroll
        for (int n = 0; n < 16; ++n) {
            float a = exp2f(dv * A2[n]);
            h[n] = fmaf(a, h[n], bc[i][n] * u);
        }
        if (PASS == 1) {
            float y = xv * Dd;
            #pragma unroll
            for (int n = 0; n < 16; ++n) y = fmaf(h[n], bc[i][16 + n], y);
            float r = b2f(xz[(size_t)l * (2 * D_INNER) + D_INNER + d]);
            float g = r * (1.0f / (1.0f + __expf(-r)));
            yg[(size_t)l * D_INNER + d] = f2b(y * g);
        }
    }
    if (PASS == 0) {
        float pr[16];
        #pragma unroll
        for (int n = 0; n < 16; ++n) pr[n] = exp2f(A2[n] * sdv);
        st_bf16x16(P + (size_t)c * DN + (size_t)d * 16, pr);
        st_bf16x16(S + (size_t)c * DN + (size_t)d * 16, h);
    }
}

// Sequential compose over chunks: h_init[c+1] = P[c]*h_init[c] + S[c].  (bf16 io)
__global__ __launch_bounds__(256)
void scan_mid(const bf16* __restrict__ P, const bf16* __restrict__ S,
              bf16* __restrict__ Hinit) {
    int idx = blockIdx.x * 256 + threadIdx.x;   // over DN
    float h = 0.0f;
    for (int c0 = 0; c0 < NCHUNK; c0 += 8) {
        float p[8], s[8];
        #pragma unroll
        for (int j = 0; j < 8; ++j) {
            p[j] = b2f(P[(size_t)(c0 + j) * DN + idx]);
            s[j] = b2f(S[(size_t)(c0 + j) * DN + idx]);
        }
        #pragma unroll
        for (int j = 0; j < 8; ++j) {
            Hinit[(size_t)(c0 + j) * DN + idx] = f2b(h);
            h = fmaf(p[j], h, s[j]);
        }
    }
}

// -------------------------------------------------------------- launcher ----
extern "C" void kernel_launch(void* const* d_in, const int* in_sizes, int n_in,
                              void* d_out, int out_size, void* d_ws, size_t ws_size,
                              hipStream_t stream) {
    const float* x       = (const float*)d_in[0];
    const float* W_in    = (const float*)d_in[1];
    const float* conv_w  = (const float*)d_in[2];
    const float* conv_b  = (const float*)d_in[3];
    const float* W_xproj = (const float*)d_in[4];
    const float* W_dt    = (const float*)d_in[5];
    const float* b_dt    = (const float*)d_in[6];
    const float* A_log   = (const float*)d_in[7];
    const float* Dw      = (const float*)d_in[8];
    const float* W_out   = (const float*)d_in[9];
    const float* norm_w  = (const float*)d_in[10];

    char* w = (char*)d_ws;
    bf16* W_in_b    = (bf16*)w; w += (size_t)2 * D_INNER * D_MODEL * 2;   // 8 MB
    bf16* W_out_b   = (bf16*)w; w += (size_t)D_MODEL * D_INNER * 2;       // 4 MB
    bf16* W_xproj_b = (bf16*)w; w += (size_t)128 * D_INNER * 2;           // 512 KB (rows 96..127 pad)
    bf16* W_dt_b    = (bf16*)w; w += (size_t)D_INNER * DT_RANK * 2;       // 256 KB
    char* reuse0 = w;   // aliased by out_part after scan
    bf16* xn        = (bf16*)w; w += (size_t)LSEQ * D_MODEL * 2;          // 4 MB
    bf16* xz        = (bf16*)w; w += (size_t)LSEQ * 2 * D_INNER * 2;      // 16 MB
    bf16* xsb       = (bf16*)w; w += (size_t)LSEQ * D_INNER * 2;          // 8 MB
    bf16* delta     = (bf16*)w; w += (size_t)LSEQ * D_INNER * 2;          // 8 MB  (36 MB pool)
    float* dbc      = (float*)w; w += (size_t)LSEQ * 96 * 4;              // 768 KB
    bf16* dtb       = (bf16*)w; w += (size_t)LSEQ * DT_RANK * 2;          // 256 KB
    bf16* yg        = (bf16*)w; w += (size_t)LSEQ * D_INNER * 2;          // 8 MB
    bf16* Pbuf      = (bf16*)w; w += (size_t)NCHUNK * DN * 2;             // 4 MB
    bf16* Sbuf      = (bf16*)w; w += (size_t)NCHUNK * DN * 2;             // 4 MB
    bf16* Hinit     = (bf16*)w; w += (size_t)NCHUNK * DN * 2;             // 4 MB
    bf16* xp_part   = (bf16*)w; w += (size_t)KSPL_X * LSEQ * 128 * 2;     // 16 MB
    bf16* out_part  = (bf16*)reuse0;   // 16 MB bf16, aliases xn/xz (dead by then)

    prep_kernel<<<LSEQ + (NCAST4 + 255) / 256, 256, 0, stream>>>(
        x, norm_w, xn, W_in, W_out, W_xproj, W_dt, W_in_b, W_out_b, W_xproj_b, W_dt_b);

    // in_proj: (2048 x 4096) = xn (2048x1024) * W_in^T
    gemm_fast<0><<<dim3(4096 / 128, 2048 / 128, 1), 512, 0, stream>>>(
        xn, W_in_b, 2048, 4096, 1024, 1024, nullptr, xz, nullptr);

    conv_kernel<<<(LSEQ / 4) * (D_INNER / 2) / 256, 256, 0, stream>>>(xz, conv_w, conv_b, xsb);

    // x_proj: (2048 x 96) = xsb (2048x2048) * W_xproj^T, split-K=32, bf16 partials
    gemm_fast<5><<<dim3(1, 2048 / 128, KSPL_X), 512, 0, stream>>>(
        xsb, W_xproj_b, 2048, 128, 2048, 2048 / KSPL_X, nullptr, xp_part, nullptr);
    reduce_xproj<<<LSEQ, 128, 0, stream>>>(xp_part, dbc, dtb);

    // delta: (2048 x 2048) = dtb (2048x64) * W_dt^T, 64x64 tiles, softplus fused
    gemm_delta<<<dim3(2048 / 64, 2048 / 64), 256, 0, stream>>>(dtb, W_dt_b, delta, b_dt);

    dim3 sgrid(D_INNER / 256, NCHUNK);
    scan2<0><<<sgrid, 256, 0, stream>>>(delta, xsb, dbc, xz, A_log, Dw,
                                        nullptr, Pbuf, Sbuf, nullptr);
    scan_mid<<<DN / 256, 256, 0, stream>>>(Pbuf, Sbuf, Hinit);
    scan2<1><<<sgrid, 256, 0, stream>>>(delta, xsb, dbc, xz, A_log, Dw,
                                        Hinit, nullptr, nullptr, yg);

    // out_proj: (2048 x 1024) = yg (2048x2048) * W_out^T, split-K=4, bf16 partials
    gemm_fast<5><<<dim3(1024 / 128, 2048 / 128, KSPL_O), 512, 0, stream>>>(
        yg, W_out_b, 2048, 1024, 2048, 2048 / KSPL_O, nullptr, out_part, nullptr);
    reduce_out<<<LSEQ * D_MODEL / 4 / 256, 256, 0, stream>>>(out_part, x, (float*)d_out);
}